// Round 5
// baseline (851.776 us; speedup 1.0000x reference)
//
#include <hip/hip_runtime.h>
#include <hip/hip_cooperative_groups.h>

namespace cg = cooperative_groups;

#define N_NODES 50000
#define N_EDGES 600000
#define D 128
#define K3 (3 * D)
#define NB_G 1563    // ceil(50000/32) gemm row-tiles
#define NREP 8       // histogram/cursor replicas (keyed by edge-unit, hist==fill)
#define NB 196       // ceil(50000/256) scan blocks
#define NBLK 768     // cooperative grid: 3 blocks/CU on 256 CUs
#define GEMM_SPLIT 600  // blocks [0,600) gemm, [600,768) hist in phase 1
#define LDSROW 104   // 96 cols + 8 pad (ushorts); row stride 208B

typedef __attribute__((ext_vector_type(8))) short short8;
typedef __attribute__((ext_vector_type(4))) float floatx4;
typedef __attribute__((ext_vector_type(8))) unsigned short ushort8;

static __device__ __forceinline__ unsigned short f2bf(float f) {
    unsigned u = __float_as_uint(f);
    u += 0x7fff + ((u >> 16) & 1);  // RNE
    return (unsigned short)(u >> 16);
}
static __device__ __forceinline__ float bf2f(unsigned short s) {
    return __uint_as_float(((unsigned)s) << 16);
}
static __device__ __forceinline__ unsigned pack2(float a, float b) {
    return (unsigned)f2bf(a) | ((unsigned)f2bf(b) << 16);
}

// ======================= cooperative mega-kernel =========================
// phase 0: zero counts8 | x->xb bf16 | W->Wr frag-order
// phase 1: gemm (blocks < GEMM_SPLIT, tiles grid-strided)  ||  hist (rest)
// phase 2: bsum   phase 3: scan_bsum (block 0)   phase 4: scan_final
// phase 5: CSR fill   phase 6: gather1 (tb = z2 + P z3)
// phase 7: gather2 (out = z1 + P tb)
__global__ __launch_bounds__(256, 4) void mega_kernel(
    const float* __restrict__ x, const float* __restrict__ W,
    const int* __restrict__ src, const int* __restrict__ dst,
    const float* __restrict__ bias, float* __restrict__ out,
    unsigned short* __restrict__ xb, unsigned short* __restrict__ z,
    unsigned short* __restrict__ tb, unsigned short* __restrict__ Wr,
    int* __restrict__ counts8, int* __restrict__ ctot,
    int* __restrict__ bsum, int* __restrict__ bexcl,
    int* __restrict__ off, int* __restrict__ cursor8,
    int* __restrict__ csr_src) {
    cg::grid_group grid = cg::this_grid();
    __shared__ unsigned short lds[4 * 32 * LDSROW];
    __shared__ int wsum[4];
    const int tid = threadIdx.x;
    const int gtid = blockIdx.x * 256 + tid;
    const int gstride = NBLK * 256;
    const int wave = tid >> 6;
    const int lane = tid & 63;
    const int col = lane & 15;
    const int quad = lane >> 4;

    // ---------------- phase 0 ----------------
    for (int i = gtid; i < NREP * N_NODES; i += gstride) counts8[i] = 0;
    for (unsigned t = gtid; t < (unsigned)N_NODES * 16; t += gstride) {
        unsigned n = t >> 4;
        unsigned c = (t & 15u) << 3;
        const float4 v0 = *(const float4*)(x + (size_t)n * D + c);
        const float4 v1 = *(const float4*)(x + (size_t)n * D + c + 4);
        ushort8 o;
        o[0] = f2bf(v0.x); o[1] = f2bf(v0.y); o[2] = f2bf(v0.z); o[3] = f2bf(v0.w);
        o[4] = f2bf(v1.x); o[5] = f2bf(v1.y); o[6] = f2bf(v1.z); o[7] = f2bf(v1.w);
        *(ushort8*)(xb + (size_t)n * D + c) = o;
    }
    // Wr chunk id = (T*4+ks)*64+lane; value[j] = W[(T&7)*16+c][(T>>3)*128+ks*32+q*8+j]
    for (unsigned id = gtid; id < 24u * 4u * 64u; id += gstride) {
        unsigned T = id >> 8;
        unsigned ks = (id >> 6) & 3u;
        unsigned ln = id & 63u;
        unsigned c = ln & 15u;
        unsigned q = ln >> 4;
        unsigned row = (T & 7u) * 16u + c;
        unsigned k = (T >> 3) * 128u + ks * 32u + q * 8u;
        const float4 v0 = *(const float4*)(W + (size_t)row * K3 + k);
        const float4 v1 = *(const float4*)(W + (size_t)row * K3 + k + 4);
        ushort8 o;
        o[0] = f2bf(v0.x); o[1] = f2bf(v0.y); o[2] = f2bf(v0.z); o[3] = f2bf(v0.w);
        o[4] = f2bf(v1.x); o[5] = f2bf(v1.y); o[6] = f2bf(v1.z); o[7] = f2bf(v1.w);
        *(ushort8*)(Wr + (size_t)id * 8) = o;
    }
    grid.sync();

    // ---------------- phase 1: gemm || hist ----------------
    if (blockIdx.x < GEMM_SPLIT) {
        for (int blk = blockIdx.x; blk < NB_G; blk += GEMM_SPLIT) {
            const int mbase = blk * 32;
            const int T0 = wave * 6;
            int r0 = mbase + col;
            int r1 = mbase + 16 + col;
            if (r0 >= N_NODES) r0 = N_NODES - 1;
            if (r1 >= N_NODES) r1 = N_NODES - 1;
            const unsigned short* ap0 = xb + (size_t)r0 * D + quad * 8;
            const unsigned short* ap1 = xb + (size_t)r1 * D + quad * 8;
            floatx4 acc0[6], acc1[6];
#pragma unroll
            for (int t = 0; t < 6; ++t) {
                acc0[t] = (floatx4){0.f, 0.f, 0.f, 0.f};
                acc1[t] = (floatx4){0.f, 0.f, 0.f, 0.f};
            }
#pragma unroll
            for (int ks = 0; ks < 4; ++ks) {
                short8 a0 = *(const short8*)(ap0 + ks * 32);
                short8 a1 = *(const short8*)(ap1 + ks * 32);
#pragma unroll
                for (int t = 0; t < 6; ++t) {
                    short8 bb = *(const short8*)(Wr + (size_t)(((T0 + t) * 4 + ks) * 64 + lane) * 8);
                    // swapped operands: lane owns 4 consecutive output cols
                    acc0[t] = __builtin_amdgcn_mfma_f32_16x16x32_bf16(bb, a0, acc0[t], 0, 0, 0);
                    acc1[t] = __builtin_amdgcn_mfma_f32_16x16x32_bf16(bb, a1, acc1[t], 0, 0, 0);
                }
            }
            // epilogue via wave-private LDS region -> coalesced 16B stores
            unsigned short* wlds = lds + wave * 32 * LDSROW;
#pragma unroll
            for (int t = 0; t < 6; ++t) {
                int T = T0 + t;
                float4 bq = (float4){0.f, 0.f, 0.f, 0.f};
                if (T < 8) bq = *(const float4*)(bias + T * 16 + quad * 4);
                uint2 p;
                p.x = pack2(acc0[t][0] + bq.x, acc0[t][1] + bq.y);
                p.y = pack2(acc0[t][2] + bq.z, acc0[t][3] + bq.w);
                *(uint2*)(wlds + col * LDSROW + t * 16 + quad * 4) = p;
                uint2 q2;
                q2.x = pack2(acc1[t][0] + bq.x, acc1[t][1] + bq.y);
                q2.y = pack2(acc1[t][2] + bq.z, acc1[t][3] + bq.w);
                *(uint2*)(wlds + (col + 16) * LDSROW + t * 16 + quad * 4) = q2;
            }
            __syncthreads();
#pragma unroll
            for (int it = 0; it < 6; ++it) {
                int id = it * 64 + lane;
                int row = id / 12;
                int ch = id - row * 12;
                int node = mbase + row;
                ushort8 v = *(const ushort8*)(wlds + row * LDSROW + ch * 8);
                if (node < N_NODES)
                    *(ushort8*)(z + (size_t)node * K3 + T0 * 16 + ch * 8) = v;
            }
            __syncthreads();  // LDS reuse across strided tiles
        }
    } else {
        // histogram: unit u = 4 edges, replica u&7 (must match fill phase)
        for (int u = (blockIdx.x - GEMM_SPLIT) * 256 + tid; u < N_EDGES / 4;
             u += (NBLK - GEMM_SPLIT) * 256) {
            int4 d4 = ((const int4*)dst)[u];
            int* base = counts8 + (u & 7) * N_NODES;
            atomicAdd(base + d4.x, 1);
            atomicAdd(base + d4.y, 1);
            atomicAdd(base + d4.z, 1);
            atomicAdd(base + d4.w, 1);
        }
    }
    grid.sync();

    // ---------------- phase 2: bsum ----------------
    if (blockIdx.x < NB) {
        int i = blockIdx.x * 256 + tid;
        int v = 0;
        if (i < N_NODES) {
#pragma unroll
            for (int r = 0; r < NREP; ++r) v += counts8[r * N_NODES + i];
            ctot[i] = v;
        }
#pragma unroll
        for (int d = 32; d >= 1; d >>= 1) v += __shfl_xor(v, d);
        if ((tid & 63) == 0) wsum[tid >> 6] = v;
        __syncthreads();
        if (tid == 0) bsum[blockIdx.x] = wsum[0] + wsum[1] + wsum[2] + wsum[3];
    }
    grid.sync();

    // ---------------- phase 3: scan_bsum (block 0) ----------------
    if (blockIdx.x == 0) {
        int v = (tid < NB) ? bsum[tid] : 0;
        int xs = v;
#pragma unroll
        for (int d = 1; d < 64; d <<= 1) {
            int u = __shfl_up(xs, d);
            if (lane >= d) xs += u;
        }
        if (lane == 63) wsum[wave] = xs;
        __syncthreads();
        int prefix = 0;
        for (int w = 0; w < wave; ++w) prefix += wsum[w];
        if (tid < NB) bexcl[tid] = prefix + xs - v;
        if (tid == 0) off[N_NODES] = N_EDGES;
    }
    grid.sync();

    // ---------------- phase 4: scan_final ----------------
    if (blockIdx.x < NB) {
        int i = blockIdx.x * 256 + tid;
        int v = (i < N_NODES) ? ctot[i] : 0;
        int xs = v;
#pragma unroll
        for (int d = 1; d < 64; d <<= 1) {
            int u = __shfl_up(xs, d);
            if (lane >= d) xs += u;
        }
        if (lane == 63) wsum[wave] = xs;
        __syncthreads();
        int prefix = 0;
        for (int w = 0; w < wave; ++w) prefix += wsum[w];
        if (i < N_NODES) {
            int excl = bexcl[blockIdx.x] + prefix + xs - v;
            off[i] = excl;
            int run = excl;
#pragma unroll
            for (int r = 0; r < NREP; ++r) {
                cursor8[r * N_NODES + i] = run;
                run += counts8[r * N_NODES + i];
            }
        }
    }
    grid.sync();

    // ---------------- phase 5: CSR fill ----------------
    for (int u = gtid; u < N_EDGES / 4; u += gstride) {
        int4 s4 = ((const int4*)src)[u];
        int4 d4 = ((const int4*)dst)[u];
        int* cbase = cursor8 + (u & 7) * N_NODES;
        csr_src[atomicAdd(cbase + d4.x, 1)] = s4.x;
        csr_src[atomicAdd(cbase + d4.y, 1)] = s4.y;
        csr_src[atomicAdd(cbase + d4.z, 1)] = s4.z;
        csr_src[atomicAdd(cbase + d4.w, 1)] = s4.w;
    }
    grid.sync();

    // ---------------- phase 6: gather1 (tb = z2 + P z3) ----------------
    {
        const int s = quad;
        const unsigned c = ((unsigned)col) << 3;
        const unsigned short* fin = z + 256 + c;  // z3 cols
        for (int n = blockIdx.x * 4 + wave; n < N_NODES; n += NBLK * 4) {
            const int2 ee = *(const int2*)(off + n);
            const int e0 = ee.x, e1 = ee.y;
            float acc[8] = {0.f, 0.f, 0.f, 0.f, 0.f, 0.f, 0.f, 0.f};
            for (int base = (e0 & ~3) + s * 4; base < e1; base += 16) {
                int4 idx = *(const int4*)(csr_src + base);
                float m0 = (base >= e0) ? 1.f : 0.f;
                float m1 = (base + 1 >= e0 && base + 1 < e1) ? 1.f : 0.f;
                float m2 = (base + 2 >= e0 && base + 2 < e1) ? 1.f : 0.f;
                float m3 = (base + 3 >= e0 && base + 3 < e1) ? 1.f : 0.f;
                int s0 = min(max(idx.x, 0), N_NODES - 1);
                int s1 = min(max(idx.y, 0), N_NODES - 1);
                int s2 = min(max(idx.z, 0), N_NODES - 1);
                int s3 = min(max(idx.w, 0), N_NODES - 1);
                ushort8 v0 = *(const ushort8*)(fin + (size_t)s0 * K3);
                ushort8 v1 = *(const ushort8*)(fin + (size_t)s1 * K3);
                ushort8 v2 = *(const ushort8*)(fin + (size_t)s2 * K3);
                ushort8 v3 = *(const ushort8*)(fin + (size_t)s3 * K3);
#pragma unroll
                for (int j = 0; j < 8; ++j)
                    acc[j] += (m0 * bf2f(v0[j]) + m1 * bf2f(v1[j])) +
                              (m2 * bf2f(v2[j]) + m3 * bf2f(v3[j]));
            }
#pragma unroll
            for (int j = 0; j < 8; ++j) {
                acc[j] += __shfl_xor(acc[j], 16);
                acc[j] += __shfl_xor(acc[j], 32);
            }
            if (s == 0) {
                float inv = 1.0f / fmaxf((float)(e1 - e0), 1.0f);
                ushort8 za = *(const ushort8*)(z + (size_t)n * K3 + 128 + c);  // z2
                ushort8 o;
#pragma unroll
                for (int j = 0; j < 8; ++j) o[j] = f2bf(bf2f(za[j]) + acc[j] * inv);
                *(ushort8*)(tb + (size_t)n * D + c) = o;
            }
        }
    }
    grid.sync();

    // ---------------- phase 7: gather2 (out = z1 + P tb) ----------------
    {
        const int s = quad;
        const unsigned c = ((unsigned)col) << 3;
        const unsigned short* fin = tb + c;
        for (int n = blockIdx.x * 4 + wave; n < N_NODES; n += NBLK * 4) {
            const int2 ee = *(const int2*)(off + n);
            const int e0 = ee.x, e1 = ee.y;
            float acc[8] = {0.f, 0.f, 0.f, 0.f, 0.f, 0.f, 0.f, 0.f};
            for (int base = (e0 & ~3) + s * 4; base < e1; base += 16) {
                int4 idx = *(const int4*)(csr_src + base);
                float m0 = (base >= e0) ? 1.f : 0.f;
                float m1 = (base + 1 >= e0 && base + 1 < e1) ? 1.f : 0.f;
                float m2 = (base + 2 >= e0 && base + 2 < e1) ? 1.f : 0.f;
                float m3 = (base + 3 >= e0 && base + 3 < e1) ? 1.f : 0.f;
                int s0 = min(max(idx.x, 0), N_NODES - 1);
                int s1 = min(max(idx.y, 0), N_NODES - 1);
                int s2 = min(max(idx.z, 0), N_NODES - 1);
                int s3 = min(max(idx.w, 0), N_NODES - 1);
                ushort8 v0 = *(const ushort8*)(fin + (size_t)s0 * D);
                ushort8 v1 = *(const ushort8*)(fin + (size_t)s1 * D);
                ushort8 v2 = *(const ushort8*)(fin + (size_t)s2 * D);
                ushort8 v3 = *(const ushort8*)(fin + (size_t)s3 * D);
#pragma unroll
                for (int j = 0; j < 8; ++j)
                    acc[j] += (m0 * bf2f(v0[j]) + m1 * bf2f(v1[j])) +
                              (m2 * bf2f(v2[j]) + m3 * bf2f(v3[j]));
            }
#pragma unroll
            for (int j = 0; j < 8; ++j) {
                acc[j] += __shfl_xor(acc[j], 16);
                acc[j] += __shfl_xor(acc[j], 32);
            }
            if (s == 0) {
                float inv = 1.0f / fmaxf((float)(e1 - e0), 1.0f);
                ushort8 za = *(const ushort8*)(z + (size_t)n * K3 + c);  // z1 (+bias)
                float4 q0, q1;
                q0.x = bf2f(za[0]) + acc[0] * inv;
                q0.y = bf2f(za[1]) + acc[1] * inv;
                q0.z = bf2f(za[2]) + acc[2] * inv;
                q0.w = bf2f(za[3]) + acc[3] * inv;
                q1.x = bf2f(za[4]) + acc[4] * inv;
                q1.y = bf2f(za[5]) + acc[5] * inv;
                q1.z = bf2f(za[6]) + acc[6] * inv;
                q1.w = bf2f(za[7]) + acc[7] * inv;
                *(float4*)(out + (size_t)n * D + c) = q0;
                *(float4*)(out + (size_t)n * D + c + 4) = q1;
            }
        }
    }
}

// ======================= fallback (9-kernel) path ========================
__global__ __launch_bounds__(256) void zero_kernel(int* __restrict__ counts8) {
    int i = blockIdx.x * 256 + threadIdx.x;
    if (i < NREP * N_NODES) counts8[i] = 0;
}

__global__ __launch_bounds__(256) void prep_kernel(const float* __restrict__ x,
                                                   const float* __restrict__ W,
                                                   const int* __restrict__ dst,
                                                   unsigned short* __restrict__ xb,
                                                   unsigned short* __restrict__ Wr,
                                                   int* __restrict__ counts8) {
    const int stride = gridDim.x * 256;
    const int t0 = blockIdx.x * 256 + threadIdx.x;
    for (int u = t0; u < N_EDGES / 4; u += stride) {
        int4 d4 = ((const int4*)dst)[u];
        int* base = counts8 + (u & 7) * N_NODES;
        atomicAdd(base + d4.x, 1);
        atomicAdd(base + d4.y, 1);
        atomicAdd(base + d4.z, 1);
        atomicAdd(base + d4.w, 1);
    }
    for (unsigned t = t0; t < (unsigned)N_NODES * 16; t += stride) {
        unsigned n = t >> 4;
        unsigned c = (t & 15u) << 3;
        const float4 v0 = *(const float4*)(x + (size_t)n * D + c);
        const float4 v1 = *(const float4*)(x + (size_t)n * D + c + 4);
        ushort8 o;
        o[0] = f2bf(v0.x); o[1] = f2bf(v0.y); o[2] = f2bf(v0.z); o[3] = f2bf(v0.w);
        o[4] = f2bf(v1.x); o[5] = f2bf(v1.y); o[6] = f2bf(v1.z); o[7] = f2bf(v1.w);
        *(ushort8*)(xb + (size_t)n * D + c) = o;
    }
    for (unsigned id = t0; id < 24u * 4u * 64u; id += stride) {
        unsigned T = id >> 8;
        unsigned ks = (id >> 6) & 3u;
        unsigned lane = id & 63u;
        unsigned c = lane & 15u;
        unsigned q = lane >> 4;
        unsigned row = (T & 7u) * 16u + c;
        unsigned k = (T >> 3) * 128u + ks * 32u + q * 8u;
        const float4 v0 = *(const float4*)(W + (size_t)row * K3 + k);
        const float4 v1 = *(const float4*)(W + (size_t)row * K3 + k + 4);
        ushort8 o;
        o[0] = f2bf(v0.x); o[1] = f2bf(v0.y); o[2] = f2bf(v0.z); o[3] = f2bf(v0.w);
        o[4] = f2bf(v1.x); o[5] = f2bf(v1.y); o[6] = f2bf(v1.z); o[7] = f2bf(v1.w);
        *(ushort8*)(Wr + (size_t)id * 8) = o;
    }
}

__global__ __launch_bounds__(256) void gemm_kernel(const unsigned short* __restrict__ xb,
                                                   const unsigned short* __restrict__ Wr,
                                                   const float* __restrict__ bias,
                                                   unsigned short* __restrict__ z) {
    __shared__ unsigned short lds[4 * 32 * LDSROW];
    const int blk = blockIdx.x;
    const int tid = threadIdx.x;
    const int wave = tid >> 6;
    const int lane = tid & 63;
    const int col = lane & 15;
    const int quad = lane >> 4;
    const int mbase = blk * 32;
    const int T0 = wave * 6;
    int r0 = mbase + col;
    int r1 = mbase + 16 + col;
    if (r0 >= N_NODES) r0 = N_NODES - 1;
    if (r1 >= N_NODES) r1 = N_NODES - 1;
    const unsigned short* ap0 = xb + (size_t)r0 * D + quad * 8;
    const unsigned short* ap1 = xb + (size_t)r1 * D + quad * 8;
    floatx4 acc0[6], acc1[6];
#pragma unroll
    for (int t = 0; t < 6; ++t) {
        acc0[t] = (floatx4){0.f, 0.f, 0.f, 0.f};
        acc1[t] = (floatx4){0.f, 0.f, 0.f, 0.f};
    }
#pragma unroll
    for (int ks = 0; ks < 4; ++ks) {
        short8 a0 = *(const short8*)(ap0 + ks * 32);
        short8 a1 = *(const short8*)(ap1 + ks * 32);
#pragma unroll
        for (int t = 0; t < 6; ++t) {
            short8 bb = *(const short8*)(Wr + (size_t)(((T0 + t) * 4 + ks) * 64 + lane) * 8);
            acc0[t] = __builtin_amdgcn_mfma_f32_16x16x32_bf16(bb, a0, acc0[t], 0, 0, 0);
            acc1[t] = __builtin_amdgcn_mfma_f32_16x16x32_bf16(bb, a1, acc1[t], 0, 0, 0);
        }
    }
    unsigned short* wlds = lds + wave * 32 * LDSROW;
#pragma unroll
    for (int t = 0; t < 6; ++t) {
        int T = T0 + t;
        float4 bq = (float4){0.f, 0.f, 0.f, 0.f};
        if (T < 8) bq = *(const float4*)(bias + T * 16 + quad * 4);
        uint2 p;
        p.x = pack2(acc0[t][0] + bq.x, acc0[t][1] + bq.y);
        p.y = pack2(acc0[t][2] + bq.z, acc0[t][3] + bq.w);
        *(uint2*)(wlds + col * LDSROW + t * 16 + quad * 4) = p;
        uint2 q2;
        q2.x = pack2(acc1[t][0] + bq.x, acc1[t][1] + bq.y);
        q2.y = pack2(acc1[t][2] + bq.z, acc1[t][3] + bq.w);
        *(uint2*)(wlds + (col + 16) * LDSROW + t * 16 + quad * 4) = q2;
    }
    __syncthreads();
#pragma unroll
    for (int it = 0; it < 6; ++it) {
        int id = it * 64 + lane;
        int row = id / 12;
        int ch = id - row * 12;
        int node = mbase + row;
        ushort8 v = *(const ushort8*)(wlds + row * LDSROW + ch * 8);
        if (node < N_NODES)
            *(ushort8*)(z + (size_t)node * K3 + T0 * 16 + ch * 8) = v;
    }
}

__global__ __launch_bounds__(256) void bsum_kernel(const int* __restrict__ counts8,
                                                   int* __restrict__ ctot,
                                                   int* __restrict__ bsum) {
    __shared__ int wsum[4];
    int tid = threadIdx.x;
    int i = blockIdx.x * 256 + tid;
    int v = 0;
    if (i < N_NODES) {
#pragma unroll
        for (int r = 0; r < NREP; ++r) v += counts8[r * N_NODES + i];
        ctot[i] = v;
    }
#pragma unroll
    for (int d = 32; d >= 1; d >>= 1) v += __shfl_xor(v, d);
    if ((tid & 63) == 0) wsum[tid >> 6] = v;
    __syncthreads();
    if (tid == 0) bsum[blockIdx.x] = wsum[0] + wsum[1] + wsum[2] + wsum[3];
}

__global__ __launch_bounds__(256) void scan_bsum_kernel(const int* __restrict__ bsum,
                                                        int* __restrict__ bexcl,
                                                        int* __restrict__ off, int nb) {
    __shared__ int wsum[4];
    int tid = threadIdx.x;
    int lane = tid & 63, wid = tid >> 6;
    int v = (tid < nb) ? bsum[tid] : 0;
    int x = v;
#pragma unroll
    for (int d = 1; d < 64; d <<= 1) {
        int u = __shfl_up(x, d);
        if (lane >= d) x += u;
    }
    if (lane == 63) wsum[wid] = x;
    __syncthreads();
    int prefix = 0;
    for (int w = 0; w < wid; ++w) prefix += wsum[w];
    if (tid < nb) bexcl[tid] = prefix + x - v;
    if (tid == 0) off[N_NODES] = N_EDGES;
}

__global__ __launch_bounds__(256) void scan_final_kernel(const int* __restrict__ ctot,
                                                         const int* __restrict__ counts8,
                                                         const int* __restrict__ bexcl,
                                                         int* __restrict__ off,
                                                         int* __restrict__ cursor8) {
    __shared__ int wsum[4];
    int tid = threadIdx.x;
    int lane = tid & 63, wid = tid >> 6;
    int i = blockIdx.x * 256 + tid;
    int v = (i < N_NODES) ? ctot[i] : 0;
    int x = v;
#pragma unroll
    for (int d = 1; d < 64; d <<= 1) {
        int u = __shfl_up(x, d);
        if (lane >= d) x += u;
    }
    if (lane == 63) wsum[wid] = x;
    __syncthreads();
    int prefix = 0;
    for (int w = 0; w < wid; ++w) prefix += wsum[w];
    if (i < N_NODES) {
        int excl = bexcl[blockIdx.x] + prefix + x - v;
        off[i] = excl;
        int run = excl;
#pragma unroll
        for (int r = 0; r < NREP; ++r) {
            cursor8[r * N_NODES + i] = run;
            run += counts8[r * N_NODES + i];
        }
    }
}

__global__ __launch_bounds__(256) void fill_kernel(const int* __restrict__ src,
                                                   const int* __restrict__ dst,
                                                   int* __restrict__ cursor8,
                                                   int* __restrict__ csr_src) {
    int u = blockIdx.x * 256 + threadIdx.x;
    if (u < N_EDGES / 4) {
        int4 s4 = ((const int4*)src)[u];
        int4 d4 = ((const int4*)dst)[u];
        int* cbase = cursor8 + (u & 7) * N_NODES;
        csr_src[atomicAdd(cbase + d4.x, 1)] = s4.x;
        csr_src[atomicAdd(cbase + d4.y, 1)] = s4.y;
        csr_src[atomicAdd(cbase + d4.z, 1)] = s4.z;
        csr_src[atomicAdd(cbase + d4.w, 1)] = s4.w;
    }
}

__global__ __launch_bounds__(256) void gather1_kernel(const unsigned short* __restrict__ z,
                                                      const int* __restrict__ off,
                                                      const int* __restrict__ csr_src,
                                                      unsigned short* __restrict__ tb) {
    unsigned n = (blockIdx.x * 256 + threadIdx.x) >> 6;
    if (n >= N_NODES) return;
    const int lane = threadIdx.x & 63;
    const int s = lane >> 4;
    const unsigned c = (lane & 15u) << 3;
    const unsigned short* fin = z + 256 + c;
    const int2 ee = *(const int2*)(off + n);
    const int e0 = ee.x, e1 = ee.y;
    float acc[8] = {0.f, 0.f, 0.f, 0.f, 0.f, 0.f, 0.f, 0.f};
    for (int base = (e0 & ~3) + s * 4; base < e1; base += 16) {
        int4 idx = *(const int4*)(csr_src + base);
        float m0 = (base >= e0) ? 1.f : 0.f;
        float m1 = (base + 1 >= e0 && base + 1 < e1) ? 1.f : 0.f;
        float m2 = (base + 2 >= e0 && base + 2 < e1) ? 1.f : 0.f;
        float m3 = (base + 3 >= e0 && base + 3 < e1) ? 1.f : 0.f;
        int s0 = min(max(idx.x, 0), N_NODES - 1);
        int s1 = min(max(idx.y, 0), N_NODES - 1);
        int s2 = min(max(idx.z, 0), N_NODES - 1);
        int s3 = min(max(idx.w, 0), N_NODES - 1);
        ushort8 v0 = *(const ushort8*)(fin + (size_t)s0 * K3);
        ushort8 v1 = *(const ushort8*)(fin + (size_t)s1 * K3);
        ushort8 v2 = *(const ushort8*)(fin + (size_t)s2 * K3);
        ushort8 v3 = *(const ushort8*)(fin + (size_t)s3 * K3);
#pragma unroll
        for (int j = 0; j < 8; ++j)
            acc[j] += (m0 * bf2f(v0[j]) + m1 * bf2f(v1[j])) +
                      (m2 * bf2f(v2[j]) + m3 * bf2f(v3[j]));
    }
#pragma unroll
    for (int j = 0; j < 8; ++j) {
        acc[j] += __shfl_xor(acc[j], 16);
        acc[j] += __shfl_xor(acc[j], 32);
    }
    if (s == 0) {
        float inv = 1.0f / fmaxf((float)(e1 - e0), 1.0f);
        ushort8 za = *(const ushort8*)(z + (size_t)n * K3 + 128 + c);
        ushort8 o;
#pragma unroll
        for (int j = 0; j < 8; ++j) o[j] = f2bf(bf2f(za[j]) + acc[j] * inv);
        *(ushort8*)(tb + (size_t)n * D + c) = o;
    }
}

__global__ __launch_bounds__(256) void gather2_kernel(const unsigned short* __restrict__ z,
                                                      const unsigned short* __restrict__ tb,
                                                      const int* __restrict__ off,
                                                      const int* __restrict__ csr_src,
                                                      float* __restrict__ out) {
    unsigned n = (blockIdx.x * 256 + threadIdx.x) >> 6;
    if (n >= N_NODES) return;
    const int lane = threadIdx.x & 63;
    const int s = lane >> 4;
    const unsigned c = (lane & 15u) << 3;
    const unsigned short* fin = tb + c;
    const int2 ee = *(const int2*)(off + n);
    const int e0 = ee.x, e1 = ee.y;
    float acc[8] = {0.f, 0.f, 0.f, 0.f, 0.f, 0.f, 0.f, 0.f};
    for (int base = (e0 & ~3) + s * 4; base < e1; base += 16) {
        int4 idx = *(const int4*)(csr_src + base);
        float m0 = (base >= e0) ? 1.f : 0.f;
        float m1 = (base + 1 >= e0 && base + 1 < e1) ? 1.f : 0.f;
        float m2 = (base + 2 >= e0 && base + 2 < e1) ? 1.f : 0.f;
        float m3 = (base + 3 >= e0 && base + 3 < e1) ? 1.f : 0.f;
        int s0 = min(max(idx.x, 0), N_NODES - 1);
        int s1 = min(max(idx.y, 0), N_NODES - 1);
        int s2 = min(max(idx.z, 0), N_NODES - 1);
        int s3 = min(max(idx.w, 0), N_NODES - 1);
        ushort8 v0 = *(const ushort8*)(fin + (size_t)s0 * D);
        ushort8 v1 = *(const ushort8*)(fin + (size_t)s1 * D);
        ushort8 v2 = *(const ushort8*)(fin + (size_t)s2 * D);
        ushort8 v3 = *(const ushort8*)(fin + (size_t)s3 * D);
#pragma unroll
        for (int j = 0; j < 8; ++j)
            acc[j] += (m0 * bf2f(v0[j]) + m1 * bf2f(v1[j])) +
                      (m2 * bf2f(v2[j]) + m3 * bf2f(v3[j]));
    }
#pragma unroll
    for (int j = 0; j < 8; ++j) {
        acc[j] += __shfl_xor(acc[j], 16);
        acc[j] += __shfl_xor(acc[j], 32);
    }
    if (s == 0) {
        float inv = 1.0f / fmaxf((float)(e1 - e0), 1.0f);
        ushort8 za = *(const ushort8*)(z + (size_t)n * K3 + c);
        float4 q0, q1;
        q0.x = bf2f(za[0]) + acc[0] * inv;
        q0.y = bf2f(za[1]) + acc[1] * inv;
        q0.z = bf2f(za[2]) + acc[2] * inv;
        q0.w = bf2f(za[3]) + acc[3] * inv;
        q1.x = bf2f(za[4]) + acc[4] * inv;
        q1.y = bf2f(za[5]) + acc[5] * inv;
        q1.z = bf2f(za[6]) + acc[6] * inv;
        q1.w = bf2f(za[7]) + acc[7] * inv;
        *(float4*)(out + (size_t)n * D + c) = q0;
        *(float4*)(out + (size_t)n * D + c + 4) = q1;
    }
}

extern "C" void kernel_launch(void* const* d_in, const int* in_sizes, int n_in,
                              void* d_out, int out_size, void* d_ws, size_t ws_size,
                              hipStream_t stream) {
    const float* x = (const float*)d_in[0];
    const int* ei = (const int*)d_in[1];
    const float* W = (const float*)d_in[2];
    const float* b = (const float*)d_in[3];
    float* out = (float*)d_out;
    const int* src = ei;            // edge_index[0,:]
    const int* dst = ei + N_EDGES;  // edge_index[1,:]

    unsigned short* xb = (unsigned short*)d_ws;
    unsigned short* z = xb + (size_t)N_NODES * D;
    unsigned short* tb = z + (size_t)N_NODES * K3;
    unsigned short* Wr = tb + (size_t)N_NODES * D;
    int* counts8 = (int*)(Wr + 6144 * 8);
    int* ctot = counts8 + NREP * N_NODES;
    int* bsumv = ctot + N_NODES;
    int* bexclv = bsumv + 256;
    int* offv = bexclv + 256;
    int* cursor8v = offv + (N_NODES + 4);  // pad keeps csr_src 16B-aligned
    int* csrv = cursor8v + NREP * N_NODES;

    void* kargs[] = {(void*)&x,      (void*)&W,     (void*)&src,    (void*)&dst,
                     (void*)&b,      (void*)&out,   (void*)&xb,     (void*)&z,
                     (void*)&tb,     (void*)&Wr,    (void*)&counts8, (void*)&ctot,
                     (void*)&bsumv,  (void*)&bexclv, (void*)&offv,  (void*)&cursor8v,
                     (void*)&csrv};
    hipError_t err = hipLaunchCooperativeKernel((void*)mega_kernel, dim3(NBLK), dim3(256),
                                                kargs, 0, stream);
    if (err != hipSuccess) {
        // fallback: proven 9-kernel pipeline
        zero_kernel<<<(NREP * N_NODES + 255) / 256, 256, 0, stream>>>(counts8);
        prep_kernel<<<800, 256, 0, stream>>>(x, W, dst, xb, Wr, counts8);
        gemm_kernel<<<NB_G, 256, 0, stream>>>(xb, Wr, b, z);
        bsum_kernel<<<NB, 256, 0, stream>>>(counts8, ctot, bsumv);
        scan_bsum_kernel<<<1, 256, 0, stream>>>(bsumv, bexclv, offv, NB);
        scan_final_kernel<<<NB, 256, 0, stream>>>(ctot, counts8, bexclv, offv, cursor8v);
        fill_kernel<<<(N_EDGES / 4 + 255) / 256, 256, 0, stream>>>(src, dst, cursor8v, csrv);
        const int ggrid = (N_NODES * 64 + 255) / 256;
        gather1_kernel<<<ggrid, 256, 0, stream>>>(z, offv, csrv, tb);
        gather2_kernel<<<ggrid, 256, 0, stream>>>(z, tb, offv, csrv, out);
    }
}

// Round 6
// 255.541 us; speedup vs baseline: 3.3332x; 3.3332x over previous
//
#include <hip/hip_runtime.h>
#include <hip/hip_cooperative_groups.h>

namespace cg = cooperative_groups;

#define N_NODES 50000
#define N_EDGES 600000
#define D 128
#define K3 (3 * D)
#define NB_G 1563   // ceil(50000/32) gemm row-tiles
#define NB_H 2344   // ceil(600000/256) hist blocks
#define NREP 8      // histogram/cursor replicas (hist block hb&7 == fill block b&7)
#define NB 196      // ceil(50000/256) scan blocks
#define LDSROW 104  // 96 cols + 8 pad (ushorts); row stride 208B

typedef __attribute__((ext_vector_type(8))) short short8;
typedef __attribute__((ext_vector_type(4))) float floatx4;
typedef __attribute__((ext_vector_type(8))) unsigned short ushort8;

static __device__ __forceinline__ unsigned short f2bf(float f) {
    unsigned u = __float_as_uint(f);
    u += 0x7fff + ((u >> 16) & 1);  // RNE
    return (unsigned short)(u >> 16);
}
static __device__ __forceinline__ float bf2f(unsigned short s) {
    return __uint_as_float(((unsigned)s) << 16);
}
static __device__ __forceinline__ unsigned pack2(float a, float b) {
    return (unsigned)f2bf(a) | ((unsigned)f2bf(b) << 16);
}

// ---------------- prep: zero counts8 | x->bf16 xb | W->frag-ordered Wr -----------
__global__ __launch_bounds__(256) void prep_kernel(const float* __restrict__ x,
                                                   const float* __restrict__ W,
                                                   unsigned short* __restrict__ xb,
                                                   unsigned short* __restrict__ Wr,
                                                   int* __restrict__ counts8) {
    const int stride = gridDim.x * 256;
    const int t0 = blockIdx.x * 256 + threadIdx.x;
    for (int i = t0; i < NREP * N_NODES; i += stride) counts8[i] = 0;
    for (unsigned t = t0; t < (unsigned)N_NODES * 16; t += stride) {
        unsigned n = t >> 4;
        unsigned c = (t & 15u) << 3;
        const float4 v0 = *(const float4*)(x + (size_t)n * D + c);
        const float4 v1 = *(const float4*)(x + (size_t)n * D + c + 4);
        ushort8 o;
        o[0] = f2bf(v0.x); o[1] = f2bf(v0.y); o[2] = f2bf(v0.z); o[3] = f2bf(v0.w);
        o[4] = f2bf(v1.x); o[5] = f2bf(v1.y); o[6] = f2bf(v1.z); o[7] = f2bf(v1.w);
        *(ushort8*)(xb + (size_t)n * D + c) = o;
    }
    // Wr chunk id = (T*4+ks)*64+lane; value[j] = W[(T&7)*16+c][(T>>3)*128+ks*32+q*8+j]
    for (unsigned id = t0; id < 24u * 4u * 64u; id += stride) {
        unsigned T = id >> 8;
        unsigned ks = (id >> 6) & 3u;
        unsigned lane = id & 63u;
        unsigned c = lane & 15u;
        unsigned q = lane >> 4;
        unsigned row = (T & 7u) * 16u + c;
        unsigned k = (T >> 3) * 128u + ks * 32u + q * 8u;
        const float4 v0 = *(const float4*)(W + (size_t)row * K3 + k);
        const float4 v1 = *(const float4*)(W + (size_t)row * K3 + k + 4);
        ushort8 o;
        o[0] = f2bf(v0.x); o[1] = f2bf(v0.y); o[2] = f2bf(v0.z); o[3] = f2bf(v0.w);
        o[4] = f2bf(v1.x); o[5] = f2bf(v1.y); o[6] = f2bf(v1.z); o[7] = f2bf(v1.w);
        *(ushort8*)(Wr + (size_t)id * 8) = o;
    }
}

// ---------------- fused: z[N,384] = xb @ Wcat^T (+bias on cols<128) | hist -------
// GEMM blocks: 32 rows/block, 4 waves; wave = 32 rows x 96 cols (6 colblocks).
// All 32 fragment loads hoisted into registers -> one load burst + 48 MFMAs.
__global__ __launch_bounds__(256) void gemmhist_kernel(const unsigned short* __restrict__ xb,
                                                       const unsigned short* __restrict__ Wr,
                                                       const float* __restrict__ bias,
                                                       const int* __restrict__ dst,
                                                       unsigned short* __restrict__ z,
                                                       int* __restrict__ counts8) {
    __shared__ unsigned short lds[4 * 32 * LDSROW];
    const int blk = blockIdx.x;
    if (blk >= NB_G) {
        int hb = blk - NB_G;
        int e = hb * 256 + threadIdx.x;
        if (e < N_EDGES) atomicAdd(&counts8[(hb & 7) * N_NODES + dst[e]], 1);
        return;
    }
    const int tid = threadIdx.x;
    const int wave = tid >> 6;
    const int lane = tid & 63;
    const int col = lane & 15;
    const int quad = lane >> 4;
    const int mbase = blk * 32;
    const int T0 = wave * 6;  // colblocks [T0, T0+6)

    int r0 = mbase + col;
    int r1 = mbase + 16 + col;
    if (r0 >= N_NODES) r0 = N_NODES - 1;  // clamp loads; stores guarded
    if (r1 >= N_NODES) r1 = N_NODES - 1;
    const unsigned short* ap0 = xb + (size_t)r0 * D + quad * 8;
    const unsigned short* ap1 = xb + (size_t)r1 * D + quad * 8;

    // hoist ALL fragment loads (static indices -> registers, no spill)
    short8 a0r[4], a1r[4];
#pragma unroll
    for (int ks = 0; ks < 4; ++ks) {
        a0r[ks] = *(const short8*)(ap0 + ks * 32);
        a1r[ks] = *(const short8*)(ap1 + ks * 32);
    }
    short8 br[24];
#pragma unroll
    for (int t = 0; t < 6; ++t)
#pragma unroll
        for (int ks = 0; ks < 4; ++ks)
            br[t * 4 + ks] = *(const short8*)(Wr + (size_t)(((T0 + t) * 4 + ks) * 64 + lane) * 8);

    floatx4 acc0[6], acc1[6];
#pragma unroll
    for (int t = 0; t < 6; ++t) {
        acc0[t] = (floatx4){0.f, 0.f, 0.f, 0.f};
        acc1[t] = (floatx4){0.f, 0.f, 0.f, 0.f};
    }
#pragma unroll
    for (int ks = 0; ks < 4; ++ks) {
#pragma unroll
        for (int t = 0; t < 6; ++t) {
            // swapped operands: output transposed -> lane owns 4 consecutive j
            acc0[t] = __builtin_amdgcn_mfma_f32_16x16x32_bf16(br[t * 4 + ks], a0r[ks], acc0[t], 0, 0, 0);
            acc1[t] = __builtin_amdgcn_mfma_f32_16x16x32_bf16(br[t * 4 + ks], a1r[ks], acc1[t], 0, 0, 0);
        }
    }

    // epilogue: lane's acc[t][r] = z[node][j], node = mbase+col (+16 for acc1),
    // j = (T0+t)*16 + quad*4 + r
    unsigned short* wlds = lds + wave * 32 * LDSROW;
#pragma unroll
    for (int t = 0; t < 6; ++t) {
        int T = T0 + t;
        float4 bq = (float4){0.f, 0.f, 0.f, 0.f};
        if (T < 8) bq = *(const float4*)(bias + T * 16 + quad * 4);
        uint2 p;
        p.x = pack2(acc0[t][0] + bq.x, acc0[t][1] + bq.y);
        p.y = pack2(acc0[t][2] + bq.z, acc0[t][3] + bq.w);
        *(uint2*)(wlds + col * LDSROW + t * 16 + quad * 4) = p;
        uint2 q2;
        q2.x = pack2(acc1[t][0] + bq.x, acc1[t][1] + bq.y);
        q2.y = pack2(acc1[t][2] + bq.z, acc1[t][3] + bq.w);
        *(uint2*)(wlds + (col + 16) * LDSROW + t * 16 + quad * 4) = q2;
    }
    __syncthreads();
    // readback: wave tile = 32 nodes x 96 cols = 384 chunks of 16B
#pragma unroll
    for (int it = 0; it < 6; ++it) {
        int id = it * 64 + lane;
        int row = id / 12;
        int ch = id - row * 12;
        int node = mbase + row;
        ushort8 v = *(const ushort8*)(wlds + row * LDSROW + ch * 8);
        if (node < N_NODES)
            *(ushort8*)(z + (size_t)node * K3 + T0 * 16 + ch * 8) = v;
    }
}

// ---------------- cooperative 3-phase scan (196 blocks, co-resident) ------------
__global__ __launch_bounds__(256) void coopscan_kernel(const int* __restrict__ counts8,
                                                       int* __restrict__ ctot,
                                                       int* __restrict__ bsum,
                                                       int* __restrict__ bexcl,
                                                       int* __restrict__ off,
                                                       int* __restrict__ cursor8) {
    cg::grid_group grid = cg::this_grid();
    __shared__ int wsum[4];
    const int tid = threadIdx.x;
    const int lane = tid & 63;
    const int wid = tid >> 6;
    const int i = blockIdx.x * 256 + tid;

    // phase A: per-node replica sum + per-block total
    int v = 0;
    if (i < N_NODES) {
#pragma unroll
        for (int r = 0; r < NREP; ++r) v += counts8[r * N_NODES + i];
        ctot[i] = v;
    }
    int rv = v;
#pragma unroll
    for (int d = 32; d >= 1; d >>= 1) rv += __shfl_xor(rv, d);
    if (lane == 0) wsum[wid] = rv;
    __syncthreads();
    if (tid == 0) bsum[blockIdx.x] = wsum[0] + wsum[1] + wsum[2] + wsum[3];
    grid.sync();

    // phase B: block 0 scans the 196 block sums
    if (blockIdx.x == 0) {
        int b = (tid < NB) ? bsum[tid] : 0;
        int xs = b;
#pragma unroll
        for (int d = 1; d < 64; d <<= 1) {
            int u = __shfl_up(xs, d);
            if (lane >= d) xs += u;
        }
        if (lane == 63) wsum[wid] = xs;
        __syncthreads();
        int prefix = 0;
        for (int w = 0; w < wid; ++w) prefix += wsum[w];
        if (tid < NB) bexcl[tid] = prefix + xs - b;
        if (tid == 0) off[N_NODES] = N_EDGES;
    }
    grid.sync();

    // phase C: final per-node exclusive scan + replica cursor bases
    int xs = v;
#pragma unroll
    for (int d = 1; d < 64; d <<= 1) {
        int u = __shfl_up(xs, d);
        if (lane >= d) xs += u;
    }
    if (lane == 63) wsum[wid] = xs;
    __syncthreads();
    int prefix = 0;
    for (int w = 0; w < wid; ++w) prefix += wsum[w];
    if (i < N_NODES) {
        int excl = bexcl[blockIdx.x] + prefix + xs - v;
        off[i] = excl;
        int run = excl;
#pragma unroll
        for (int r = 0; r < NREP; ++r) {
            cursor8[r * N_NODES + i] = run;
            run += counts8[r * N_NODES + i];
        }
    }
}

// ---------------- fallback scan kernels (if coop launch rejected) ----------------
__global__ __launch_bounds__(256) void bsum_kernel(const int* __restrict__ counts8,
                                                   int* __restrict__ ctot,
                                                   int* __restrict__ bsum) {
    __shared__ int wsum[4];
    int tid = threadIdx.x;
    int i = blockIdx.x * 256 + tid;
    int v = 0;
    if (i < N_NODES) {
#pragma unroll
        for (int r = 0; r < NREP; ++r) v += counts8[r * N_NODES + i];
        ctot[i] = v;
    }
#pragma unroll
    for (int d = 32; d >= 1; d >>= 1) v += __shfl_xor(v, d);
    if ((tid & 63) == 0) wsum[tid >> 6] = v;
    __syncthreads();
    if (tid == 0) bsum[blockIdx.x] = wsum[0] + wsum[1] + wsum[2] + wsum[3];
}

__global__ __launch_bounds__(256) void scan_bsum_kernel(const int* __restrict__ bsum,
                                                        int* __restrict__ bexcl,
                                                        int* __restrict__ off, int nb) {
    __shared__ int wsum[4];
    int tid = threadIdx.x;
    int lane = tid & 63, wid = tid >> 6;
    int v = (tid < nb) ? bsum[tid] : 0;
    int x = v;
#pragma unroll
    for (int d = 1; d < 64; d <<= 1) {
        int u = __shfl_up(x, d);
        if (lane >= d) x += u;
    }
    if (lane == 63) wsum[wid] = x;
    __syncthreads();
    int prefix = 0;
    for (int w = 0; w < wid; ++w) prefix += wsum[w];
    if (tid < nb) bexcl[tid] = prefix + x - v;
    if (tid == 0) off[N_NODES] = N_EDGES;
}

__global__ __launch_bounds__(256) void scan_final_kernel(const int* __restrict__ ctot,
                                                         const int* __restrict__ counts8,
                                                         const int* __restrict__ bexcl,
                                                         int* __restrict__ off,
                                                         int* __restrict__ cursor8) {
    __shared__ int wsum[4];
    int tid = threadIdx.x;
    int lane = tid & 63, wid = tid >> 6;
    int i = blockIdx.x * 256 + tid;
    int v = (i < N_NODES) ? ctot[i] : 0;
    int x = v;
#pragma unroll
    for (int d = 1; d < 64; d <<= 1) {
        int u = __shfl_up(x, d);
        if (lane >= d) x += u;
    }
    if (lane == 63) wsum[wid] = x;
    __syncthreads();
    int prefix = 0;
    for (int w = 0; w < wid; ++w) prefix += wsum[w];
    if (i < N_NODES) {
        int excl = bexcl[blockIdx.x] + prefix + x - v;
        off[i] = excl;
        int run = excl;
#pragma unroll
        for (int r = 0; r < NREP; ++r) {
            cursor8[r * N_NODES + i] = run;
            run += counts8[r * N_NODES + i];
        }
    }
}

// ---------------- CSR fill (replica r = blockIdx&7 == hist hb&7) ----------------
__global__ __launch_bounds__(256) void fill_kernel(const int* __restrict__ src,
                                                   const int* __restrict__ dst,
                                                   int* __restrict__ cursor8,
                                                   int* __restrict__ csr_src) {
    int e = blockIdx.x * blockDim.x + threadIdx.x;
    if (e < N_EDGES) {
        int r = blockIdx.x & 7;
        int pos = atomicAdd(&cursor8[r * N_NODES + dst[e]], 1);
        csr_src[pos] = src[e];
    }
}

// ---------------- gather1: tb = z2 + P z3  (bf16 out) ----------------
__global__ __launch_bounds__(256) void gather1_kernel(const unsigned short* __restrict__ z,
                                                      const int* __restrict__ off,
                                                      const int* __restrict__ csr_src,
                                                      unsigned short* __restrict__ tb) {
    unsigned n = (blockIdx.x * 256 + threadIdx.x) >> 6;
    if (n >= N_NODES) return;
    const int lane = threadIdx.x & 63;
    const int s = lane >> 4;
    const unsigned c = (lane & 15u) << 3;
    const unsigned short* fin = z + 256 + c;  // z3 cols
    const int2 ee = *(const int2*)(off + n);
    const int e0 = ee.x, e1 = ee.y;
    float acc[8] = {0.f, 0.f, 0.f, 0.f, 0.f, 0.f, 0.f, 0.f};
    for (int base = (e0 & ~3) + s * 4; base < e1; base += 16) {
        int4 idx = *(const int4*)(csr_src + base);
        float m0 = (base >= e0) ? 1.f : 0.f;
        float m1 = (base + 1 >= e0 && base + 1 < e1) ? 1.f : 0.f;
        float m2 = (base + 2 >= e0 && base + 2 < e1) ? 1.f : 0.f;
        float m3 = (base + 3 >= e0 && base + 3 < e1) ? 1.f : 0.f;
        int s0 = min(max(idx.x, 0), N_NODES - 1);
        int s1 = min(max(idx.y, 0), N_NODES - 1);
        int s2 = min(max(idx.z, 0), N_NODES - 1);
        int s3 = min(max(idx.w, 0), N_NODES - 1);
        ushort8 v0 = *(const ushort8*)(fin + (size_t)s0 * K3);
        ushort8 v1 = *(const ushort8*)(fin + (size_t)s1 * K3);
        ushort8 v2 = *(const ushort8*)(fin + (size_t)s2 * K3);
        ushort8 v3 = *(const ushort8*)(fin + (size_t)s3 * K3);
#pragma unroll
        for (int j = 0; j < 8; ++j)
            acc[j] += (m0 * bf2f(v0[j]) + m1 * bf2f(v1[j])) +
                      (m2 * bf2f(v2[j]) + m3 * bf2f(v3[j]));
    }
#pragma unroll
    for (int j = 0; j < 8; ++j) {
        acc[j] += __shfl_xor(acc[j], 16);
        acc[j] += __shfl_xor(acc[j], 32);
    }
    if (s == 0) {
        float inv = 1.0f / fmaxf((float)(e1 - e0), 1.0f);
        ushort8 za = *(const ushort8*)(z + (size_t)n * K3 + 128 + c);  // z2
        ushort8 o;
#pragma unroll
        for (int j = 0; j < 8; ++j) o[j] = f2bf(bf2f(za[j]) + acc[j] * inv);
        *(ushort8*)(tb + (size_t)n * D + c) = o;
    }
}

// ---------------- gather2: out = z1 + P tb  (fp32 out, final) ----------------
__global__ __launch_bounds__(256) void gather2_kernel(const unsigned short* __restrict__ z,
                                                      const unsigned short* __restrict__ tb,
                                                      const int* __restrict__ off,
                                                      const int* __restrict__ csr_src,
                                                      float* __restrict__ out) {
    unsigned n = (blockIdx.x * 256 + threadIdx.x) >> 6;
    if (n >= N_NODES) return;
    const int lane = threadIdx.x & 63;
    const int s = lane >> 4;
    const unsigned c = (lane & 15u) << 3;
    const unsigned short* fin = tb + c;
    const int2 ee = *(const int2*)(off + n);
    const int e0 = ee.x, e1 = ee.y;
    float acc[8] = {0.f, 0.f, 0.f, 0.f, 0.f, 0.f, 0.f, 0.f};
    for (int base = (e0 & ~3) + s * 4; base < e1; base += 16) {
        int4 idx = *(const int4*)(csr_src + base);
        float m0 = (base >= e0) ? 1.f : 0.f;
        float m1 = (base + 1 >= e0 && base + 1 < e1) ? 1.f : 0.f;
        float m2 = (base + 2 >= e0 && base + 2 < e1) ? 1.f : 0.f;
        float m3 = (base + 3 >= e0 && base + 3 < e1) ? 1.f : 0.f;
        int s0 = min(max(idx.x, 0), N_NODES - 1);
        int s1 = min(max(idx.y, 0), N_NODES - 1);
        int s2 = min(max(idx.z, 0), N_NODES - 1);
        int s3 = min(max(idx.w, 0), N_NODES - 1);
        ushort8 v0 = *(const ushort8*)(fin + (size_t)s0 * D);
        ushort8 v1 = *(const ushort8*)(fin + (size_t)s1 * D);
        ushort8 v2 = *(const ushort8*)(fin + (size_t)s2 * D);
        ushort8 v3 = *(const ushort8*)(fin + (size_t)s3 * D);
#pragma unroll
        for (int j = 0; j < 8; ++j)
            acc[j] += (m0 * bf2f(v0[j]) + m1 * bf2f(v1[j])) +
                      (m2 * bf2f(v2[j]) + m3 * bf2f(v3[j]));
    }
#pragma unroll
    for (int j = 0; j < 8; ++j) {
        acc[j] += __shfl_xor(acc[j], 16);
        acc[j] += __shfl_xor(acc[j], 32);
    }
    if (s == 0) {
        float inv = 1.0f / fmaxf((float)(e1 - e0), 1.0f);
        ushort8 za = *(const ushort8*)(z + (size_t)n * K3 + c);  // z1 (+bias)
        float4 q0, q1;
        q0.x = bf2f(za[0]) + acc[0] * inv;
        q0.y = bf2f(za[1]) + acc[1] * inv;
        q0.z = bf2f(za[2]) + acc[2] * inv;
        q0.w = bf2f(za[3]) + acc[3] * inv;
        q1.x = bf2f(za[4]) + acc[4] * inv;
        q1.y = bf2f(za[5]) + acc[5] * inv;
        q1.z = bf2f(za[6]) + acc[6] * inv;
        q1.w = bf2f(za[7]) + acc[7] * inv;
        *(float4*)(out + (size_t)n * D + c) = q0;
        *(float4*)(out + (size_t)n * D + c + 4) = q1;
    }
}

extern "C" void kernel_launch(void* const* d_in, const int* in_sizes, int n_in,
                              void* d_out, int out_size, void* d_ws, size_t ws_size,
                              hipStream_t stream) {
    const float* x = (const float*)d_in[0];
    const int* ei = (const int*)d_in[1];
    const float* W = (const float*)d_in[2];
    const float* b = (const float*)d_in[3];
    float* out = (float*)d_out;
    const int* src = ei;            // edge_index[0,:]
    const int* dst = ei + N_EDGES;  // edge_index[1,:]

    // workspace layout:
    //   xb [N,128] bf16 | z [N,384] bf16 | tb [N,128] bf16 | Wr 6144x16B
    //   counts8 [8N] | ctot [N] | bsum/bexcl [256+256] | off [N+1 pad N+4]
    //   cursor8 [8N] | csr_src [E+16]
    unsigned short* xb = (unsigned short*)d_ws;
    unsigned short* z = xb + (size_t)N_NODES * D;
    unsigned short* tb = z + (size_t)N_NODES * K3;
    unsigned short* Wr = tb + (size_t)N_NODES * D;
    int* counts8 = (int*)(Wr + 6144 * 8);
    int* ctot = counts8 + NREP * N_NODES;
    int* bsumv = ctot + N_NODES;
    int* bexclv = bsumv + 256;
    int* offv = bexclv + 256;
    int* cursor8v = offv + (N_NODES + 4);  // pad keeps csr_src 16B-aligned
    int* csrv = cursor8v + NREP * N_NODES;

    prep_kernel<<<800, 256, 0, stream>>>(x, W, xb, Wr, counts8);
    gemmhist_kernel<<<NB_G + NB_H, 256, 0, stream>>>(xb, Wr, b, dst, z, counts8);

    {
        const int* c8 = counts8;
        void* kargs[] = {(void*)&c8,    (void*)&ctot,  (void*)&bsumv,
                         (void*)&bexclv, (void*)&offv, (void*)&cursor8v};
        hipError_t err = hipLaunchCooperativeKernel((void*)coopscan_kernel, dim3(NB),
                                                    dim3(256), kargs, 0, stream);
        if (err != hipSuccess) {
            bsum_kernel<<<NB, 256, 0, stream>>>(counts8, ctot, bsumv);
            scan_bsum_kernel<<<1, 256, 0, stream>>>(bsumv, bexclv, offv, NB);
            scan_final_kernel<<<NB, 256, 0, stream>>>(ctot, counts8, bexclv, offv, cursor8v);
        }
    }

    fill_kernel<<<(N_EDGES + 255) / 256, 256, 0, stream>>>(src, dst, cursor8v, csrv);

    const int ggrid = (N_NODES * 64 + 255) / 256;  // one wave per node
    gather1_kernel<<<ggrid, 256, 0, stream>>>(z, offv, csrv, tb);
    gather2_kernel<<<ggrid, 256, 0, stream>>>(z, tb, offv, csrv, out);
}

// Round 7
// 208.832 us; speedup vs baseline: 4.0788x; 1.2237x over previous
//
#include <hip/hip_runtime.h>

#define N_NODES 50000
#define N_EDGES 600000
#define D 128
#define K3 (3 * D)
#define NB_G 1563   // ceil(50000/32) gemm row-tiles
#define NB_H 2344   // ceil(600000/256) hist blocks
#define NREP 8      // histogram/cursor replicas; key r=(e>>2)&7 (hist==fill)
#define NB 196      // ceil(50000/256) scan blocks
#define LDSROW 104  // 96 cols + 8 pad (ushorts); row stride 208B

typedef __attribute__((ext_vector_type(8))) short short8;
typedef __attribute__((ext_vector_type(4))) float floatx4;
typedef __attribute__((ext_vector_type(8))) unsigned short ushort8;

static __device__ __forceinline__ unsigned short f2bf(float f) {
    unsigned u = __float_as_uint(f);
    u += 0x7fff + ((u >> 16) & 1);  // RNE
    return (unsigned short)(u >> 16);
}
static __device__ __forceinline__ float bf2f(unsigned short s) {
    return __uint_as_float(((unsigned)s) << 16);
}
static __device__ __forceinline__ unsigned pack2(float a, float b) {
    return (unsigned)f2bf(a) | ((unsigned)f2bf(b) << 16);
}

// ---------------- prep: zero counts8 | x->bf16 xb | W->frag-ordered Wr -----------
__global__ __launch_bounds__(256) void prep_kernel(const float* __restrict__ x,
                                                   const float* __restrict__ W,
                                                   unsigned short* __restrict__ xb,
                                                   unsigned short* __restrict__ Wr,
                                                   int* __restrict__ counts8) {
    const int stride = gridDim.x * 256;
    const int t0 = blockIdx.x * 256 + threadIdx.x;
    for (int i = t0; i < NREP * N_NODES; i += stride) counts8[i] = 0;
    for (unsigned t = t0; t < (unsigned)N_NODES * 16; t += stride) {
        unsigned n = t >> 4;
        unsigned c = (t & 15u) << 3;
        const float4 v0 = *(const float4*)(x + (size_t)n * D + c);
        const float4 v1 = *(const float4*)(x + (size_t)n * D + c + 4);
        ushort8 o;
        o[0] = f2bf(v0.x); o[1] = f2bf(v0.y); o[2] = f2bf(v0.z); o[3] = f2bf(v0.w);
        o[4] = f2bf(v1.x); o[5] = f2bf(v1.y); o[6] = f2bf(v1.z); o[7] = f2bf(v1.w);
        *(ushort8*)(xb + (size_t)n * D + c) = o;
    }
    // Wr chunk id = (T*4+ks)*64+lane; value[j] = W[(T&7)*16+c][(T>>3)*128+ks*32+q*8+j]
    for (unsigned id = t0; id < 24u * 4u * 64u; id += stride) {
        unsigned T = id >> 8;
        unsigned ks = (id >> 6) & 3u;
        unsigned lane = id & 63u;
        unsigned c = lane & 15u;
        unsigned q = lane >> 4;
        unsigned row = (T & 7u) * 16u + c;
        unsigned k = (T >> 3) * 128u + ks * 32u + q * 8u;
        const float4 v0 = *(const float4*)(W + (size_t)row * K3 + k);
        const float4 v1 = *(const float4*)(W + (size_t)row * K3 + k + 4);
        ushort8 o;
        o[0] = f2bf(v0.x); o[1] = f2bf(v0.y); o[2] = f2bf(v0.z); o[3] = f2bf(v0.w);
        o[4] = f2bf(v1.x); o[5] = f2bf(v1.y); o[6] = f2bf(v1.z); o[7] = f2bf(v1.w);
        *(ushort8*)(Wr + (size_t)id * 8) = o;
    }
}

// ---------------- fused: z[N,384] = xb @ Wcat^T (+bias on cols<128) | hist -------
// GEMM blocks: 32 rows/block, 4 waves; wave = 32 rows x 96 cols (6 colblocks).
// All 32 fragment loads hoisted into registers -> one load burst + 48 MFMAs.
// Hist: replica key r=(e>>2)&7 (MUST match fill_kernel's unit key).
__global__ __launch_bounds__(256) void gemmhist_kernel(const unsigned short* __restrict__ xb,
                                                       const unsigned short* __restrict__ Wr,
                                                       const float* __restrict__ bias,
                                                       const int* __restrict__ dst,
                                                       unsigned short* __restrict__ z,
                                                       int* __restrict__ counts8) {
    __shared__ unsigned short lds[4 * 32 * LDSROW];
    const int blk = blockIdx.x;
    if (blk >= NB_G) {
        int e = (blk - NB_G) * 256 + threadIdx.x;
        if (e < N_EDGES) atomicAdd(&counts8[((e >> 2) & 7) * N_NODES + dst[e]], 1);
        return;
    }
    const int tid = threadIdx.x;
    const int wave = tid >> 6;
    const int lane = tid & 63;
    const int col = lane & 15;
    const int quad = lane >> 4;
    const int mbase = blk * 32;
    const int T0 = wave * 6;  // colblocks [T0, T0+6)

    int r0 = mbase + col;
    int r1 = mbase + 16 + col;
    if (r0 >= N_NODES) r0 = N_NODES - 1;  // clamp loads; stores guarded
    if (r1 >= N_NODES) r1 = N_NODES - 1;
    const unsigned short* ap0 = xb + (size_t)r0 * D + quad * 8;
    const unsigned short* ap1 = xb + (size_t)r1 * D + quad * 8;

    // hoist ALL fragment loads (static indices -> registers, no spill)
    short8 a0r[4], a1r[4];
#pragma unroll
    for (int ks = 0; ks < 4; ++ks) {
        a0r[ks] = *(const short8*)(ap0 + ks * 32);
        a1r[ks] = *(const short8*)(ap1 + ks * 32);
    }
    short8 br[24];
#pragma unroll
    for (int t = 0; t < 6; ++t)
#pragma unroll
        for (int ks = 0; ks < 4; ++ks)
            br[t * 4 + ks] = *(const short8*)(Wr + (size_t)(((T0 + t) * 4 + ks) * 64 + lane) * 8);

    floatx4 acc0[6], acc1[6];
#pragma unroll
    for (int t = 0; t < 6; ++t) {
        acc0[t] = (floatx4){0.f, 0.f, 0.f, 0.f};
        acc1[t] = (floatx4){0.f, 0.f, 0.f, 0.f};
    }
#pragma unroll
    for (int ks = 0; ks < 4; ++ks) {
#pragma unroll
        for (int t = 0; t < 6; ++t) {
            // swapped operands: output transposed -> lane owns 4 consecutive j
            acc0[t] = __builtin_amdgcn_mfma_f32_16x16x32_bf16(br[t * 4 + ks], a0r[ks], acc0[t], 0, 0, 0);
            acc1[t] = __builtin_amdgcn_mfma_f32_16x16x32_bf16(br[t * 4 + ks], a1r[ks], acc1[t], 0, 0, 0);
        }
    }

    // epilogue: lane's acc[t][r] = z[node][j], node = mbase+col (+16 for acc1),
    // j = (T0+t)*16 + quad*4 + r
    unsigned short* wlds = lds + wave * 32 * LDSROW;
#pragma unroll
    for (int t = 0; t < 6; ++t) {
        int T = T0 + t;
        float4 bq = (float4){0.f, 0.f, 0.f, 0.f};
        if (T < 8) bq = *(const float4*)(bias + T * 16 + quad * 4);
        uint2 p;
        p.x = pack2(acc0[t][0] + bq.x, acc0[t][1] + bq.y);
        p.y = pack2(acc0[t][2] + bq.z, acc0[t][3] + bq.w);
        *(uint2*)(wlds + col * LDSROW + t * 16 + quad * 4) = p;
        uint2 q2;
        q2.x = pack2(acc1[t][0] + bq.x, acc1[t][1] + bq.y);
        q2.y = pack2(acc1[t][2] + bq.z, acc1[t][3] + bq.w);
        *(uint2*)(wlds + (col + 16) * LDSROW + t * 16 + quad * 4) = q2;
    }
    __syncthreads();
    // readback: wave tile = 32 nodes x 96 cols = 384 chunks of 16B
#pragma unroll
    for (int it = 0; it < 6; ++it) {
        int id = it * 64 + lane;
        int row = id / 12;
        int ch = id - row * 12;
        int node = mbase + row;
        ushort8 v = *(const ushort8*)(wlds + row * LDSROW + ch * 8);
        if (node < N_NODES)
            *(ushort8*)(z + (size_t)node * K3 + T0 * 16 + ch * 8) = v;
    }
}

// ---------------- 3-phase scan over replica-summed counts (proven) --------------
__global__ __launch_bounds__(256) void bsum_kernel(const int* __restrict__ counts8,
                                                   int* __restrict__ ctot,
                                                   int* __restrict__ bsum) {
    __shared__ int wsum[4];
    int tid = threadIdx.x;
    int i = blockIdx.x * 256 + tid;
    int v = 0;
    if (i < N_NODES) {
#pragma unroll
        for (int r = 0; r < NREP; ++r) v += counts8[r * N_NODES + i];
        ctot[i] = v;
    }
#pragma unroll
    for (int d = 32; d >= 1; d >>= 1) v += __shfl_xor(v, d);
    if ((tid & 63) == 0) wsum[tid >> 6] = v;
    __syncthreads();
    if (tid == 0) bsum[blockIdx.x] = wsum[0] + wsum[1] + wsum[2] + wsum[3];
}

__global__ __launch_bounds__(256) void scan_bsum_kernel(const int* __restrict__ bsum,
                                                        int* __restrict__ bexcl,
                                                        int* __restrict__ off, int nb) {
    __shared__ int wsum[4];
    int tid = threadIdx.x;
    int lane = tid & 63, wid = tid >> 6;
    int v = (tid < nb) ? bsum[tid] : 0;
    int x = v;
#pragma unroll
    for (int d = 1; d < 64; d <<= 1) {
        int u = __shfl_up(x, d);
        if (lane >= d) x += u;
    }
    if (lane == 63) wsum[wid] = x;
    __syncthreads();
    int prefix = 0;
    for (int w = 0; w < wid; ++w) prefix += wsum[w];
    if (tid < nb) bexcl[tid] = prefix + x - v;
    if (tid == 0) off[N_NODES] = N_EDGES;
}

__global__ __launch_bounds__(256) void scan_final_kernel(const int* __restrict__ ctot,
                                                         const int* __restrict__ counts8,
                                                         const int* __restrict__ bexcl,
                                                         int* __restrict__ off,
                                                         int* __restrict__ cursor8) {
    __shared__ int wsum[4];
    int tid = threadIdx.x;
    int lane = tid & 63, wid = tid >> 6;
    int i = blockIdx.x * 256 + tid;
    int v = (i < N_NODES) ? ctot[i] : 0;
    int x = v;
#pragma unroll
    for (int d = 1; d < 64; d <<= 1) {
        int u = __shfl_up(x, d);
        if (lane >= d) x += u;
    }
    if (lane == 63) wsum[wid] = x;
    __syncthreads();
    int prefix = 0;
    for (int w = 0; w < wid; ++w) prefix += wsum[w];
    if (i < N_NODES) {
        int excl = bexcl[blockIdx.x] + prefix + x - v;
        off[i] = excl;
        int run = excl;
#pragma unroll
        for (int r = 0; r < NREP; ++r) {
            cursor8[r * N_NODES + i] = run;
            run += counts8[r * N_NODES + i];
        }
    }
}

// -------- CSR fill: 4 edges/thread, replica key u&7 == (e>>2)&7 == hist key -----
__global__ __launch_bounds__(256) void fill_kernel(const int* __restrict__ src,
                                                   const int* __restrict__ dst,
                                                   int* __restrict__ cursor8,
                                                   int* __restrict__ csr_src) {
    int u = blockIdx.x * 256 + threadIdx.x;
    if (u < N_EDGES / 4) {
        int4 s4 = ((const int4*)src)[u];
        int4 d4 = ((const int4*)dst)[u];
        int* cbase = cursor8 + (u & 7) * N_NODES;
        csr_src[atomicAdd(cbase + d4.x, 1)] = s4.x;
        csr_src[atomicAdd(cbase + d4.y, 1)] = s4.y;
        csr_src[atomicAdd(cbase + d4.z, 1)] = s4.z;
        csr_src[atomicAdd(cbase + d4.w, 1)] = s4.w;
    }
}

// ---------------- gather1: tb = z2 + P z3  (bf16 out) ----------------
// one wave/node; lane = slot*16 + colchunk; int4-aligned index group loads.
__global__ __launch_bounds__(256) void gather1_kernel(const unsigned short* __restrict__ z,
                                                      const int* __restrict__ off,
                                                      const int* __restrict__ csr_src,
                                                      unsigned short* __restrict__ tb) {
    unsigned n = (blockIdx.x * 256 + threadIdx.x) >> 6;
    if (n >= N_NODES) return;
    const int lane = threadIdx.x & 63;
    const int s = lane >> 4;
    const unsigned c = (lane & 15u) << 3;
    const unsigned short* fin = z + 256 + c;  // z3 cols
    const int2 ee = *(const int2*)(off + n);
    const int e0 = ee.x, e1 = ee.y;
    float acc[8] = {0.f, 0.f, 0.f, 0.f, 0.f, 0.f, 0.f, 0.f};
    for (int base = (e0 & ~3) + s * 4; base < e1; base += 16) {
        int4 idx = *(const int4*)(csr_src + base);
        float m0 = (base >= e0) ? 1.f : 0.f;
        float m1 = (base + 1 >= e0 && base + 1 < e1) ? 1.f : 0.f;
        float m2 = (base + 2 >= e0 && base + 2 < e1) ? 1.f : 0.f;
        float m3 = (base + 3 >= e0 && base + 3 < e1) ? 1.f : 0.f;
        int s0 = min(max(idx.x, 0), N_NODES - 1);
        int s1 = min(max(idx.y, 0), N_NODES - 1);
        int s2 = min(max(idx.z, 0), N_NODES - 1);
        int s3 = min(max(idx.w, 0), N_NODES - 1);
        ushort8 v0 = *(const ushort8*)(fin + (size_t)s0 * K3);
        ushort8 v1 = *(const ushort8*)(fin + (size_t)s1 * K3);
        ushort8 v2 = *(const ushort8*)(fin + (size_t)s2 * K3);
        ushort8 v3 = *(const ushort8*)(fin + (size_t)s3 * K3);
#pragma unroll
        for (int j = 0; j < 8; ++j)
            acc[j] += (m0 * bf2f(v0[j]) + m1 * bf2f(v1[j])) +
                      (m2 * bf2f(v2[j]) + m3 * bf2f(v3[j]));
    }
#pragma unroll
    for (int j = 0; j < 8; ++j) {
        acc[j] += __shfl_xor(acc[j], 16);
        acc[j] += __shfl_xor(acc[j], 32);
    }
    if (s == 0) {
        float inv = 1.0f / fmaxf((float)(e1 - e0), 1.0f);
        ushort8 za = *(const ushort8*)(z + (size_t)n * K3 + 128 + c);  // z2
        ushort8 o;
#pragma unroll
        for (int j = 0; j < 8; ++j) o[j] = f2bf(bf2f(za[j]) + acc[j] * inv);
        *(ushort8*)(tb + (size_t)n * D + c) = o;
    }
}

// ---------------- gather2: out = z1 + P tb  (fp32 out, final) ----------------
__global__ __launch_bounds__(256) void gather2_kernel(const unsigned short* __restrict__ z,
                                                      const unsigned short* __restrict__ tb,
                                                      const int* __restrict__ off,
                                                      const int* __restrict__ csr_src,
                                                      float* __restrict__ out) {
    unsigned n = (blockIdx.x * 256 + threadIdx.x) >> 6;
    if (n >= N_NODES) return;
    const int lane = threadIdx.x & 63;
    const int s = lane >> 4;
    const unsigned c = (lane & 15u) << 3;
    const unsigned short* fin = tb + c;
    const int2 ee = *(const int2*)(off + n);
    const int e0 = ee.x, e1 = ee.y;
    float acc[8] = {0.f, 0.f, 0.f, 0.f, 0.f, 0.f, 0.f, 0.f};
    for (int base = (e0 & ~3) + s * 4; base < e1; base += 16) {
        int4 idx = *(const int4*)(csr_src + base);
        float m0 = (base >= e0) ? 1.f : 0.f;
        float m1 = (base + 1 >= e0 && base + 1 < e1) ? 1.f : 0.f;
        float m2 = (base + 2 >= e0 && base + 2 < e1) ? 1.f : 0.f;
        float m3 = (base + 3 >= e0 && base + 3 < e1) ? 1.f : 0.f;
        int s0 = min(max(idx.x, 0), N_NODES - 1);
        int s1 = min(max(idx.y, 0), N_NODES - 1);
        int s2 = min(max(idx.z, 0), N_NODES - 1);
        int s3 = min(max(idx.w, 0), N_NODES - 1);
        ushort8 v0 = *(const ushort8*)(fin + (size_t)s0 * D);
        ushort8 v1 = *(const ushort8*)(fin + (size_t)s1 * D);
        ushort8 v2 = *(const ushort8*)(fin + (size_t)s2 * D);
        ushort8 v3 = *(const ushort8*)(fin + (size_t)s3 * D);
#pragma unroll
        for (int j = 0; j < 8; ++j)
            acc[j] += (m0 * bf2f(v0[j]) + m1 * bf2f(v1[j])) +
                      (m2 * bf2f(v2[j]) + m3 * bf2f(v3[j]));
    }
#pragma unroll
    for (int j = 0; j < 8; ++j) {
        acc[j] += __shfl_xor(acc[j], 16);
        acc[j] += __shfl_xor(acc[j], 32);
    }
    if (s == 0) {
        float inv = 1.0f / fmaxf((float)(e1 - e0), 1.0f);
        ushort8 za = *(const ushort8*)(z + (size_t)n * K3 + c);  // z1 (+bias)
        float4 q0, q1;
        q0.x = bf2f(za[0]) + acc[0] * inv;
        q0.y = bf2f(za[1]) + acc[1] * inv;
        q0.z = bf2f(za[2]) + acc[2] * inv;
        q0.w = bf2f(za[3]) + acc[3] * inv;
        q1.x = bf2f(za[4]) + acc[4] * inv;
        q1.y = bf2f(za[5]) + acc[5] * inv;
        q1.z = bf2f(za[6]) + acc[6] * inv;
        q1.w = bf2f(za[7]) + acc[7] * inv;
        *(float4*)(out + (size_t)n * D + c) = q0;
        *(float4*)(out + (size_t)n * D + c + 4) = q1;
    }
}

extern "C" void kernel_launch(void* const* d_in, const int* in_sizes, int n_in,
                              void* d_out, int out_size, void* d_ws, size_t ws_size,
                              hipStream_t stream) {
    const float* x = (const float*)d_in[0];
    const int* ei = (const int*)d_in[1];
    const float* W = (const float*)d_in[2];
    const float* b = (const float*)d_in[3];
    float* out = (float*)d_out;
    const int* src = ei;            // edge_index[0,:]
    const int* dst = ei + N_EDGES;  // edge_index[1,:]

    // workspace layout:
    //   xb [N,128] bf16 | z [N,384] bf16 | tb [N,128] bf16 | Wr 6144x16B
    //   counts8 [8N] | ctot [N] | bsum/bexcl [256+256] | off [N+1 pad N+4]
    //   cursor8 [8N] | csr_src [E+16]
    unsigned short* xb = (unsigned short*)d_ws;
    unsigned short* z = xb + (size_t)N_NODES * D;
    unsigned short* tb = z + (size_t)N_NODES * K3;
    unsigned short* Wr = tb + (size_t)N_NODES * D;
    int* counts8 = (int*)(Wr + 6144 * 8);
    int* ctot = counts8 + NREP * N_NODES;
    int* bsumv = ctot + N_NODES;
    int* bexclv = bsumv + 256;
    int* offv = bexclv + 256;
    int* cursor8v = offv + (N_NODES + 4);  // pad keeps csr_src 16B-aligned
    int* csrv = cursor8v + NREP * N_NODES;

    prep_kernel<<<800, 256, 0, stream>>>(x, W, xb, Wr, counts8);
    gemmhist_kernel<<<NB_G + NB_H, 256, 0, stream>>>(xb, Wr, b, dst, z, counts8);
    bsum_kernel<<<NB, 256, 0, stream>>>(counts8, ctot, bsumv);
    scan_bsum_kernel<<<1, 256, 0, stream>>>(bsumv, bexclv, offv, NB);
    scan_final_kernel<<<NB, 256, 0, stream>>>(ctot, counts8, bexclv, offv, cursor8v);
    fill_kernel<<<(N_EDGES / 4 + 255) / 256, 256, 0, stream>>>(src, dst, cursor8v, csrv);

    const int ggrid = (N_NODES * 64 + 255) / 256;  // one wave per node
    gather1_kernel<<<ggrid, 256, 0, stream>>>(z, offv, csrv, tb);
    gather2_kernel<<<ggrid, 256, 0, stream>>>(z, tb, offv, csrv, out);
}

// Round 8
// 188.484 us; speedup vs baseline: 4.5191x; 1.1080x over previous
//
#include <hip/hip_runtime.h>

#define N_NODES 50000
#define N_EDGES 600000
#define D 128
#define K3 (3 * D)
#define CAP 64      // bucket capacity per node (mean deg 12; spill path for overflow)
#define SM 4        // strips of 32 rows per gemm block
#define NB_G2 391   // ceil(50000/128)
#define LDSROW 104  // 96 cols + 8 pad (ushorts); row stride 208B

typedef __attribute__((ext_vector_type(8))) short short8;
typedef __attribute__((ext_vector_type(4))) float floatx4;
typedef __attribute__((ext_vector_type(8))) unsigned short ushort8;

static __device__ __forceinline__ unsigned short f2bf(float f) {
    unsigned u = __float_as_uint(f);
    u += 0x7fff + ((u >> 16) & 1);  // RNE
    return (unsigned short)(u >> 16);
}
static __device__ __forceinline__ float bf2f(unsigned short s) {
    return __uint_as_float(((unsigned)s) << 16);
}
static __device__ __forceinline__ unsigned pack2(float a, float b) {
    return (unsigned)f2bf(a) | ((unsigned)f2bf(b) << 16);
}

// ---------------- prep: zero cnt+ovfcnt | x->bf16 xb | W->frag-ordered Wr --------
__global__ __launch_bounds__(256) void prep_kernel(const float* __restrict__ x,
                                                   const float* __restrict__ W,
                                                   unsigned short* __restrict__ xb,
                                                   unsigned short* __restrict__ Wr,
                                                   int* __restrict__ cnt) {
    const int stride = gridDim.x * 256;
    const int t0 = blockIdx.x * 256 + threadIdx.x;
    for (int i = t0; i < N_NODES + 4; i += stride) cnt[i] = 0;  // cnt[N] + ovfcnt
    for (unsigned t = t0; t < (unsigned)N_NODES * 16; t += stride) {
        unsigned n = t >> 4;
        unsigned c = (t & 15u) << 3;
        const float4 v0 = *(const float4*)(x + (size_t)n * D + c);
        const float4 v1 = *(const float4*)(x + (size_t)n * D + c + 4);
        ushort8 o;
        o[0] = f2bf(v0.x); o[1] = f2bf(v0.y); o[2] = f2bf(v0.z); o[3] = f2bf(v0.w);
        o[4] = f2bf(v1.x); o[5] = f2bf(v1.y); o[6] = f2bf(v1.z); o[7] = f2bf(v1.w);
        *(ushort8*)(xb + (size_t)n * D + c) = o;
    }
    // Wr chunk id = (T*4+ks)*64+lane; value[j] = W[(T&7)*16+c][(T>>3)*128+ks*32+q*8+j]
    for (unsigned id = t0; id < 24u * 4u * 64u; id += stride) {
        unsigned T = id >> 8;
        unsigned ks = (id >> 6) & 3u;
        unsigned lane = id & 63u;
        unsigned c = lane & 15u;
        unsigned q = lane >> 4;
        unsigned row = (T & 7u) * 16u + c;
        unsigned k = (T >> 3) * 128u + ks * 32u + q * 8u;
        const float4 v0 = *(const float4*)(W + (size_t)row * K3 + k);
        const float4 v1 = *(const float4*)(W + (size_t)row * K3 + k + 4);
        ushort8 o;
        o[0] = f2bf(v0.x); o[1] = f2bf(v0.y); o[2] = f2bf(v0.z); o[3] = f2bf(v0.w);
        o[4] = f2bf(v1.x); o[5] = f2bf(v1.y); o[6] = f2bf(v1.z); o[7] = f2bf(v1.w);
        *(ushort8*)(Wr + (size_t)id * 8) = o;
    }
}

// -------- bucket-CSR fill: atomic IS the cursor (no hist, no scans) -------------
__global__ __launch_bounds__(256) void fillb_kernel(const int* __restrict__ src,
                                                    const int* __restrict__ dst,
                                                    int* __restrict__ cnt,
                                                    int* __restrict__ bucket,
                                                    int2* __restrict__ ovf) {
    int* ovfcnt = cnt + N_NODES;
    int u = blockIdx.x * 256 + threadIdx.x;
    if (u < N_EDGES / 4) {
        int4 s4 = ((const int4*)src)[u];
        int4 d4 = ((const int4*)dst)[u];
        int p0 = atomicAdd(&cnt[d4.x], 1);
        if (p0 < CAP) bucket[(size_t)d4.x * CAP + p0] = s4.x;
        else ovf[atomicAdd(ovfcnt, 1)] = make_int2(d4.x, s4.x);
        int p1 = atomicAdd(&cnt[d4.y], 1);
        if (p1 < CAP) bucket[(size_t)d4.y * CAP + p1] = s4.y;
        else ovf[atomicAdd(ovfcnt, 1)] = make_int2(d4.y, s4.y);
        int p2 = atomicAdd(&cnt[d4.z], 1);
        if (p2 < CAP) bucket[(size_t)d4.z * CAP + p2] = s4.z;
        else ovf[atomicAdd(ovfcnt, 1)] = make_int2(d4.z, s4.z);
        int p3 = atomicAdd(&cnt[d4.w], 1);
        if (p3 < CAP) bucket[(size_t)d4.w * CAP + p3] = s4.w;
        else ovf[atomicAdd(ovfcnt, 1)] = make_int2(d4.w, s4.w);
    }
}

// ------- strip-mined GEMM: z[N,384] = xb @ Wcat^T (+bias cols<128) --------------
// 391 blocks x 4 strips of 32 rows; br[24] (96 VGPR) loaded ONCE per wave ->
// Wr L2 traffic 150MB -> 19MB. Block-wide LDS readback -> full-row 768B stores.
__global__ __launch_bounds__(256) void gemm_kernel(const unsigned short* __restrict__ xb,
                                                   const unsigned short* __restrict__ Wr,
                                                   const float* __restrict__ bias,
                                                   unsigned short* __restrict__ z) {
    __shared__ unsigned short lds[4 * 32 * LDSROW];
    const int tid = threadIdx.x;
    const int wave = tid >> 6;
    const int lane = tid & 63;
    const int col = lane & 15;
    const int quad = lane >> 4;
    const int T0 = wave * 6;  // colblocks [T0, T0+6) => global cols [wave*96, +96)

    // persistent B fragments for this wave's 96 columns
    short8 br[24];
#pragma unroll
    for (int t = 0; t < 6; ++t)
#pragma unroll
        for (int ks = 0; ks < 4; ++ks)
            br[t * 4 + ks] = *(const short8*)(Wr + (size_t)(((T0 + t) * 4 + ks) * 64 + lane) * 8);

    float4 bq = (float4){0.f, 0.f, 0.f, 0.f};  // bias for z1 cols (T<8)
    // per-t bias loaded inside epilogue below (depends on t)

    unsigned short* wlds = lds + wave * 32 * LDSROW;

    for (int sidx = 0; sidx < SM; ++sidx) {
        const int mbase = blockIdx.x * (SM * 32) + sidx * 32;
        int r0 = mbase + col;
        int r1 = mbase + 16 + col;
        if (r0 >= N_NODES) r0 = N_NODES - 1;  // clamp loads; stores guarded
        if (r1 >= N_NODES) r1 = N_NODES - 1;
        const unsigned short* ap0 = xb + (size_t)r0 * D + quad * 8;
        const unsigned short* ap1 = xb + (size_t)r1 * D + quad * 8;
        short8 a0r[4], a1r[4];
#pragma unroll
        for (int ks = 0; ks < 4; ++ks) {
            a0r[ks] = *(const short8*)(ap0 + ks * 32);
            a1r[ks] = *(const short8*)(ap1 + ks * 32);
        }

        floatx4 acc0[6], acc1[6];
#pragma unroll
        for (int t = 0; t < 6; ++t) {
            acc0[t] = (floatx4){0.f, 0.f, 0.f, 0.f};
            acc1[t] = (floatx4){0.f, 0.f, 0.f, 0.f};
        }
#pragma unroll
        for (int ks = 0; ks < 4; ++ks) {
#pragma unroll
            for (int t = 0; t < 6; ++t) {
                // swapped operands: lane owns 4 consecutive output cols
                acc0[t] = __builtin_amdgcn_mfma_f32_16x16x32_bf16(br[t * 4 + ks], a0r[ks], acc0[t], 0, 0, 0);
                acc1[t] = __builtin_amdgcn_mfma_f32_16x16x32_bf16(br[t * 4 + ks], a1r[ks], acc1[t], 0, 0, 0);
            }
        }

        // epilogue: lane's acc[t][r] = z[node][j], node=mbase+col (+16), j=(T0+t)*16+quad*4+r
#pragma unroll
        for (int t = 0; t < 6; ++t) {
            int T = T0 + t;
            bq = (float4){0.f, 0.f, 0.f, 0.f};
            if (T < 8) bq = *(const float4*)(bias + T * 16 + quad * 4);
            uint2 p;
            p.x = pack2(acc0[t][0] + bq.x, acc0[t][1] + bq.y);
            p.y = pack2(acc0[t][2] + bq.z, acc0[t][3] + bq.w);
            *(uint2*)(wlds + col * LDSROW + t * 16 + quad * 4) = p;
            uint2 q2;
            q2.x = pack2(acc1[t][0] + bq.x, acc1[t][1] + bq.y);
            q2.y = pack2(acc1[t][2] + bq.z, acc1[t][3] + bq.w);
            *(uint2*)(wlds + (col + 16) * LDSROW + t * 16 + quad * 4) = q2;
        }
        __syncthreads();
        // block-wide readback: 32 rows x 48 chunks(16B) = full 768B rows, coalesced
#pragma unroll
        for (int it = 0; it < 6; ++it) {
            int id = it * 256 + tid;
            int row = id / 48;
            int ch = id - row * 48;
            int w = ch / 12;
            int cc = (ch - w * 12) * 8;  // ushort offset within wave's 96 cols
            int node = mbase + row;
            ushort8 v = *(const ushort8*)(lds + (size_t)w * 32 * LDSROW + row * LDSROW + cc);
            if (node < N_NODES)
                *(ushort8*)(z + (size_t)node * K3 + ch * 8) = v;
        }
        __syncthreads();
    }
}

// ---------------- gather1: tb = z2 + P z3  (bf16 out) ----------------
// one wave/node; lane = slot*16 + colchunk; bucket rows are 16B-aligned.
__global__ __launch_bounds__(256) void gather1_kernel(const unsigned short* __restrict__ z,
                                                      const int* __restrict__ cnt,
                                                      const int* __restrict__ bucket,
                                                      const int2* __restrict__ ovf,
                                                      unsigned short* __restrict__ tb) {
    unsigned n = (blockIdx.x * 256 + threadIdx.x) >> 6;
    if (n >= N_NODES) return;
    const int lane = threadIdx.x & 63;
    const int s = lane >> 4;
    const unsigned c = (lane & 15u) << 3;
    const unsigned short* fin = z + 256 + c;  // z3 cols
    const int deg = cnt[n];
    const int dcap = min(deg, CAP);
    const int* bp = bucket + (size_t)n * CAP;
    float acc[8] = {0.f, 0.f, 0.f, 0.f, 0.f, 0.f, 0.f, 0.f};
    for (int base = s * 4; base < dcap; base += 16) {
        int4 idx = *(const int4*)(bp + base);
        float m0 = 1.f;  // base < dcap guaranteed
        float m1 = (base + 1 < dcap) ? 1.f : 0.f;
        float m2 = (base + 2 < dcap) ? 1.f : 0.f;
        float m3 = (base + 3 < dcap) ? 1.f : 0.f;
        int s0 = min(max(idx.x, 0), N_NODES - 1);
        int s1 = min(max(idx.y, 0), N_NODES - 1);
        int s2 = min(max(idx.z, 0), N_NODES - 1);
        int s3 = min(max(idx.w, 0), N_NODES - 1);
        ushort8 v0 = *(const ushort8*)(fin + (size_t)s0 * K3);
        ushort8 v1 = *(const ushort8*)(fin + (size_t)s1 * K3);
        ushort8 v2 = *(const ushort8*)(fin + (size_t)s2 * K3);
        ushort8 v3 = *(const ushort8*)(fin + (size_t)s3 * K3);
#pragma unroll
        for (int j = 0; j < 8; ++j)
            acc[j] += (m0 * bf2f(v0[j]) + m1 * bf2f(v1[j])) +
                      (m2 * bf2f(v2[j]) + m3 * bf2f(v3[j]));
    }
    if (deg > CAP) {  // spill path (never taken for this input; correct in general)
        int oc = cnt[N_NODES];
        if (s == 0)
            for (int i = 0; i < oc; ++i) {
                int2 p = ovf[i];
                if (p.x == (int)n) {
                    ushort8 v = *(const ushort8*)(fin + (size_t)p.y * K3);
#pragma unroll
                    for (int j = 0; j < 8; ++j) acc[j] += bf2f(v[j]);
                }
            }
    }
#pragma unroll
    for (int j = 0; j < 8; ++j) {
        acc[j] += __shfl_xor(acc[j], 16);
        acc[j] += __shfl_xor(acc[j], 32);
    }
    if (s == 0) {
        float inv = 1.0f / fmaxf((float)deg, 1.0f);
        ushort8 za = *(const ushort8*)(z + (size_t)n * K3 + 128 + c);  // z2
        ushort8 o;
#pragma unroll
        for (int j = 0; j < 8; ++j) o[j] = f2bf(bf2f(za[j]) + acc[j] * inv);
        *(ushort8*)(tb + (size_t)n * D + c) = o;
    }
}

// ---------------- gather2: out = z1 + P tb  (fp32 out, final) ----------------
__global__ __launch_bounds__(256) void gather2_kernel(const unsigned short* __restrict__ z,
                                                      const unsigned short* __restrict__ tb,
                                                      const int* __restrict__ cnt,
                                                      const int* __restrict__ bucket,
                                                      const int2* __restrict__ ovf,
                                                      float* __restrict__ out) {
    unsigned n = (blockIdx.x * 256 + threadIdx.x) >> 6;
    if (n >= N_NODES) return;
    const int lane = threadIdx.x & 63;
    const int s = lane >> 4;
    const unsigned c = (lane & 15u) << 3;
    const unsigned short* fin = tb + c;
    const int deg = cnt[n];
    const int dcap = min(deg, CAP);
    const int* bp = bucket + (size_t)n * CAP;
    float acc[8] = {0.f, 0.f, 0.f, 0.f, 0.f, 0.f, 0.f, 0.f};
    for (int base = s * 4; base < dcap; base += 16) {
        int4 idx = *(const int4*)(bp + base);
        float m0 = 1.f;
        float m1 = (base + 1 < dcap) ? 1.f : 0.f;
        float m2 = (base + 2 < dcap) ? 1.f : 0.f;
        float m3 = (base + 3 < dcap) ? 1.f : 0.f;
        int s0 = min(max(idx.x, 0), N_NODES - 1);
        int s1 = min(max(idx.y, 0), N_NODES - 1);
        int s2 = min(max(idx.z, 0), N_NODES - 1);
        int s3 = min(max(idx.w, 0), N_NODES - 1);
        ushort8 v0 = *(const ushort8*)(fin + (size_t)s0 * D);
        ushort8 v1 = *(const ushort8*)(fin + (size_t)s1 * D);
        ushort8 v2 = *(const ushort8*)(fin + (size_t)s2 * D);
        ushort8 v3 = *(const ushort8*)(fin + (size_t)s3 * D);
#pragma unroll
        for (int j = 0; j < 8; ++j)
            acc[j] += (m0 * bf2f(v0[j]) + m1 * bf2f(v1[j])) +
                      (m2 * bf2f(v2[j]) + m3 * bf2f(v3[j]));
    }
    if (deg > CAP) {
        int oc = cnt[N_NODES];
        if (s == 0)
            for (int i = 0; i < oc; ++i) {
                int2 p = ovf[i];
                if (p.x == (int)n) {
                    ushort8 v = *(const ushort8*)(fin + (size_t)p.y * D);
#pragma unroll
                    for (int j = 0; j < 8; ++j) acc[j] += bf2f(v[j]);
                }
            }
    }
#pragma unroll
    for (int j = 0; j < 8; ++j) {
        acc[j] += __shfl_xor(acc[j], 16);
        acc[j] += __shfl_xor(acc[j], 32);
    }
    if (s == 0) {
        float inv = 1.0f / fmaxf((float)deg, 1.0f);
        ushort8 za = *(const ushort8*)(z + (size_t)n * K3 + c);  // z1 (+bias)
        float4 q0, q1;
        q0.x = bf2f(za[0]) + acc[0] * inv;
        q0.y = bf2f(za[1]) + acc[1] * inv;
        q0.z = bf2f(za[2]) + acc[2] * inv;
        q0.w = bf2f(za[3]) + acc[3] * inv;
        q1.x = bf2f(za[4]) + acc[4] * inv;
        q1.y = bf2f(za[5]) + acc[5] * inv;
        q1.z = bf2f(za[6]) + acc[6] * inv;
        q1.w = bf2f(za[7]) + acc[7] * inv;
        *(float4*)(out + (size_t)n * D + c) = q0;
        *(float4*)(out + (size_t)n * D + c + 4) = q1;
    }
}

extern "C" void kernel_launch(void* const* d_in, const int* in_sizes, int n_in,
                              void* d_out, int out_size, void* d_ws, size_t ws_size,
                              hipStream_t stream) {
    const float* x = (const float*)d_in[0];
    const int* ei = (const int*)d_in[1];
    const float* W = (const float*)d_in[2];
    const float* b = (const float*)d_in[3];
    float* out = (float*)d_out;
    const int* src = ei;            // edge_index[0,:]
    const int* dst = ei + N_EDGES;  // edge_index[1,:]

    // workspace layout:
    //   xb [N,128] bf16 | z [N,384] bf16 | tb [N,128] bf16 | Wr 6144x16B
    //   cnt [N] + ovfcnt [4] | bucket [N*64] | ovf [E int2]
    unsigned short* xb = (unsigned short*)d_ws;
    unsigned short* z = xb + (size_t)N_NODES * D;
    unsigned short* tb = z + (size_t)N_NODES * K3;
    unsigned short* Wr = tb + (size_t)N_NODES * D;
    int* cnt = (int*)(Wr + 6144 * 8);
    int* bucket = cnt + N_NODES + 4;          // 16B-aligned (N+4 ints from aligned base)
    int2* ovf = (int2*)(bucket + (size_t)N_NODES * CAP);

    prep_kernel<<<800, 256, 0, stream>>>(x, W, xb, Wr, cnt);
    fillb_kernel<<<(N_EDGES / 4 + 255) / 256, 256, 0, stream>>>(src, dst, cnt, bucket, ovf);
    gemm_kernel<<<NB_G2, 256, 0, stream>>>(xb, Wr, b, z);

    const int ggrid = (N_NODES * 64 + 255) / 256;  // one wave per node
    gather1_kernel<<<ggrid, 256, 0, stream>>>(z, cnt, bucket, ovf, tb);
    gather2_kernel<<<ggrid, 256, 0, stream>>>(z, tb, cnt, bucket, ovf, out);
}